// Round 10
// baseline (258.164 us; speedup 1.0000x reference)
//
#include <hip/hip_runtime.h>

#define NN 20000
#define COLS 32

typedef _Float16 f16x2 __attribute__((ext_vector_type(2)));
typedef unsigned short u16x2 __attribute__((ext_vector_type(2)));

union U32H2 { unsigned int u; f16x2 h; };
union U32S2 { unsigned int u; u16x2 s; };

__device__ __forceinline__ f16x2 bc_h2(unsigned int u) { U32H2 x; x.u = u; return x.h; }
__device__ __forceinline__ unsigned int dup_h(float v) {
    _Float16 h = (_Float16)v;
    unsigned short b = __builtin_bit_cast(unsigned short, h);
    return ((unsigned int)b << 16) | b;
}
__device__ __forceinline__ unsigned int pkrtz_u32(float a, float b) {
    return __builtin_bit_cast(unsigned int, __builtin_amdgcn_cvt_pkrtz(a, b));
}

template <int CTRL>
__device__ __forceinline__ unsigned int pkmax_dpp(unsigned int v) {
    unsigned int d = (unsigned int)__builtin_amdgcn_update_dpp(
        0, (int)v, CTRL, 0xF, 0xF, true);
    U32S2 a, b; a.u = v; b.u = d;
    a.s = __builtin_elementwise_max(a.s, b.s);
    return a.u;
}
__device__ __forceinline__ unsigned int octmax_u16x2(unsigned int v) {
    v = pkmax_dpp<0xB1>(v);    // quad_perm xor1
    v = pkmax_dpp<0x4E>(v);    // quad_perm xor2
    v = pkmax_dpp<0x141>(v);   // row_half_mirror (xor4 within 8)
    return v;
}

// ---------------- prep: softmax(W) -> packed-f16 pi tables ----------------
__global__ __launch_bounds__(1024) void prep_kernel(const float* __restrict__ W,
                                                    unsigned int* __restrict__ pi_pk,
                                                    unsigned int* __restrict__ pi_t_pk,
                                                    unsigned int* __restrict__ pi1_pk,
                                                    unsigned int* __restrict__ pi2_pk) {
    __shared__ float red[1024];
    __shared__ float piL[4096];
    int t = threadIdx.x;
    float4 wv = ((const float4*)W)[t];
    float m = fmaxf(fmaxf(wv.x, wv.y), fmaxf(wv.z, wv.w));
    red[t] = m; __syncthreads();
    for (int s = 512; s > 0; s >>= 1) {
        if (t < s) red[t] = fmaxf(red[t], red[t + s]);
        __syncthreads();
    }
    m = red[0];
    __syncthreads();
    float e0 = expf(wv.x - m), e1 = expf(wv.y - m);
    float e2 = expf(wv.z - m), e3 = expf(wv.w - m);
    red[t] = e0 + e1 + e2 + e3;
    __syncthreads();
    for (int s = 512; s > 0; s >>= 1) {
        if (t < s) red[t] += red[t + s];
        __syncthreads();
    }
    float inv = 1.0f / red[0];
    float p[4] = { e0 * inv, e1 * inv, e2 * inv, e3 * inv };
#pragma unroll
    for (int i = 0; i < 4; i++) {
        int f = t * 4 + i;
        piL[f] = p[i];
        unsigned int d = dup_h(p[i]);
        pi_pk[f] = d;
        pi_t_pk[(f & 63) * 64 + (f >> 6)] = d;  // transposed [k][j]
    }
    __syncthreads();
    if (t < 64) {
        float s = 0.f;
        for (int k = 0; k < 64; k++) s += piL[t * 64 + k];
        pi1_pk[t] = dup_h(s);
    } else if (t < 128) {
        int k = t - 64;
        float s = 0.f;
        for (int j = 0; j < 64; j++) s += piL[j * 64 + k];
        pi2_pk[k] = dup_h(s);
    }
}

// ---------------- pack a0 fp32 (B,N) planes -> u8x4 table ----------------
__global__ __launch_bounds__(1024) void pack_kernel(const float* __restrict__ a0,
                                                    unsigned int* __restrict__ T0) {
    int i = blockIdx.x * 1024 + threadIdx.x;
    if (i < NN) {
        unsigned int b0 = __float2uint_rn(__saturatef(a0[i]) * 255.0f);
        unsigned int b1 = __float2uint_rn(__saturatef(a0[NN + i]) * 255.0f);
        unsigned int b2 = __float2uint_rn(__saturatef(a0[2 * NN + i]) * 255.0f);
        unsigned int b3 = __float2uint_rn(__saturatef(a0[3 * NN + i]) * 255.0f);
        T0[i] = b0 | (b1 << 8) | (b2 << 16) | (b3 << 24);
    }
}

// ---------------- phase 1: clause gathers into one Ft buffer ----------------
__device__ __forceinline__ void phase1(
    const unsigned int* __restrict__ tab,
    unsigned int (* __restrict__ Ftb)[COLS][2],
    const int* __restrict__ X1, const int* __restrict__ X2,
    int nb, int cn, int widu, int ni, int w) {
    const float sc = 1.0f / 65025.0f;
    int loff[4];
#pragma unroll
    for (int oc = 0; oc < 4; ++oc) {
        int n = nb + oc * 8 + ni;
        int nc = n < NN ? n : NN - 1;
        loff[oc] = nc * 64 + w * 8;
    }
    int2 q5[4];
    {
        const int row = widu, k = row & 63;
        const char* Xb = (const char*)((row >> 6) ? X2 : X1) + (unsigned)(k * NN) * 64u;
#pragma unroll
        for (int oc = 0; oc < 4; ++oc) q5[oc] = *(const int2*)(Xb + loff[oc]);
    }
#pragma unroll
    for (int rr = 0; rr < 8; ++rr) {
        int2 qn[4];
        if (rr < 7) {
            const int row = widu + 16 * (rr + 1), k = row & 63;
            const char* Xb = (const char*)((row >> 6) ? X2 : X1) + (unsigned)(k * NN) * 64u;
#pragma unroll
            for (int oc = 0; oc < 4; ++oc) qn[oc] = *(const int2*)(Xb + loff[oc]);
        }
        const int row = widu + 16 * rr;
        unsigned int ga[4], gb[4];
#pragma unroll
        for (int oc = 0; oc < 4; ++oc) { ga[oc] = tab[q5[oc].x]; gb[oc] = tab[q5[oc].y]; }
#pragma unroll
        for (int oc = 0; oc < 4; ++oc) {
            unsigned int ea = ga[oc] & 0x00FF00FFu;
            unsigned int oa = (ga[oc] >> 8) & 0x00FF00FFu;
            unsigned int eb = gb[oc] & 0x00FF00FFu;
            unsigned int ob = (gb[oc] >> 8) & 0x00FF00FFu;
            U32S2 pe, po, xb;
            pe.u = ea; xb.u = eb; pe.s = pe.s * xb.s;
            po.u = oa; xb.u = ob; po.s = po.s * xb.s;
            unsigned int peu = octmax_u16x2(pe.u);
            unsigned int pou = octmax_u16x2(po.u);
            int col = oc * 8 + ni;
            if (w == 0 && col < cn) {
                float f0 = (float)(peu & 0xFFFFu) * sc;   // b0
                float f1 = (float)(pou & 0xFFFFu) * sc;   // b1
                float f2 = (float)(peu >> 16) * sc;       // b2
                float f3 = (float)(pou >> 16) * sc;       // b3
                *(uint2*)&Ftb[row][col][0] =
                    make_uint2(pkrtz_u32(f0, f1), pkrtz_u32(f2, f3));
            }
        }
#pragma unroll
        for (int oc = 0; oc < 4; ++oc) q5[oc] = qn[oc];
    }
}

// ---------------- phase 2: bilinear partials for (qu, bp, n_l) ----------------
__device__ __forceinline__ float2 phase2(
    const unsigned int (* __restrict__ Ftb)[COLS][2],
    const unsigned int* __restrict__ pi_t_pk,
    const unsigned int* __restrict__ pi1_pk,
    const unsigned int* __restrict__ pi2_pk,
    int qu, int bp, int n_l) {
    f16x2 zero = {(_Float16)0, (_Float16)0};
    f16x2 f1v[8];
    f16x2 eu = zero;
#pragma unroll
    for (int jj = 0; jj < 8; ++jj) {
        f1v[jj] = bc_h2(Ftb[qu * 8 + jj][n_l][bp]);
        eu += bc_h2(pi1_pk[qu * 8 + jj]) * f1v[jj];  // s_load
    }
    f16x2 euv = zero, ev = zero;
#pragma unroll 8
    for (int k = 0; k < 64; ++k) {
        f16x2 f2 = bc_h2(Ftb[64 + k][n_l][bp]);
        const uint4* pt = (const uint4*)(pi_t_pk + k * 64 + qu * 8);
        uint4 w0 = pt[0], w1 = pt[1];  // scalar addr -> s_load_dwordx4
        f16x2 ts = bc_h2(w0.x) * f1v[0] + bc_h2(w0.y) * f1v[1] +
                   bc_h2(w0.z) * f1v[2] + bc_h2(w0.w) * f1v[3] +
                   bc_h2(w1.x) * f1v[4] + bc_h2(w1.y) * f1v[5] +
                   bc_h2(w1.z) * f1v[6] + bc_h2(w1.w) * f1v[7];
        euv += f2 * ts;
        if (qu == 0) ev += bc_h2(pi2_pk[k]) * f2;
    }
    float p0 = (float)eu[0] - (float)euv[0];
    float p1 = (float)eu[1] - (float)euv[1];
    if (qu == 0) { p0 += (float)ev[0]; p1 += (float)ev[1]; }
    return make_float2(p0, p1);
}

// ---------------- fused, software-pipelined iteration ----------------
// Super-step c: phase2(chunk c, buf cur) -> phase1(chunk c+1, buf cur^1)
// -> barrier -> combine(c). Both pipe-heavy sections share one barrier
// interval, so waves slip and LDS/VMEM (phase1) overlaps VALU (phase2).
template <int ITER>
__global__ __launch_bounds__(1024, 4) void fused_iter(
    const unsigned int* __restrict__ Tsrc,
    const int* __restrict__ X1, const int* __restrict__ X2,
    const unsigned int* __restrict__ pi_t_pk,
    const unsigned int* __restrict__ pi1_pk,
    const unsigned int* __restrict__ pi2_pk,
    const float* __restrict__ a0,
    unsigned int* __restrict__ Tdst, float* __restrict__ outP) {
    __shared__ unsigned int tab[NN];               // 80,000 B
    __shared__ unsigned int Ft[2][128][COLS][2];   // 65,536 B
    __shared__ float redp[2][8][COLS][4];          //  8,192 B

    const int t = threadIdx.x;
    for (int i = t; i < NN; i += 1024) tab[i] = Tsrc[i];

    const int bid = (int)blockIdx.x;
    const int bstart = bid < 32 ? bid * 79 : 32 * 79 + (bid - 32) * 78;
    const int bcnt = bid < 32 ? 79 : 78;
    const int nbs[3] = { bstart, bstart + 32, bstart + 64 };
    const int cns[3] = { 32, 32, bcnt - 64 };

    const int wid = t >> 6, lane = t & 63, ni = lane >> 3, w = lane & 7;
    const int q = t >> 7, bp = (t >> 6) & 1, n_l = t & 63;
    const int widu = __builtin_amdgcn_readfirstlane(wid);
    const int qu = __builtin_amdgcn_readfirstlane(q);

    __syncthreads();                                   // tab ready
    phase1(tab, Ft[0], X1, X2, nbs[0], cns[0], widu, ni, w);
    __syncthreads();                                   // buf0 ready

    for (int c = 0; c < 3; ++c) {
        const int cur = c & 1;
        if (n_l < cns[c]) {
            float2 pp = phase2(Ft[cur], pi_t_pk, pi1_pk, pi2_pk, qu, bp, n_l);
            *(float2*)&redp[cur][q][n_l][bp * 2] = pp;
        }
        if (c < 2)
            phase1(tab, Ft[cur ^ 1], X1, X2, nbs[c + 1], cns[c + 1], widu, ni, w);
        __syncthreads();
        // combine chunk c (redp[cur] stable; rewritten only at c+2, after
        // the next barrier, so no extra barrier needed here)
        if (t < cns[c]) {
            int gn = nbs[c] + t;
            float d0 = 0.f, d1 = 0.f, d2 = 0.f, d3 = 0.f;
#pragma unroll
            for (int q8 = 0; q8 < 8; ++q8) {
                d0 += redp[cur][q8][t][0];
                d1 += redp[cur][q8][t][1];
                d2 += redp[cur][q8][t][2];
                d3 += redp[cur][q8][t][3];
            }
            float ap0, ap1, ap2, ap3;
            if (ITER == 1) {
                ap0 = a0[gn]; ap1 = a0[NN + gn];
                ap2 = a0[2 * NN + gn]; ap3 = a0[3 * NN + gn];
            } else {
                unsigned int tv = tab[gn];
                ap0 = (float)(tv & 255u) * (1.0f / 255.0f);
                ap1 = (float)((tv >> 8) & 255u) * (1.0f / 255.0f);
                ap2 = (float)((tv >> 16) & 255u) * (1.0f / 255.0f);
                ap3 = (float)(tv >> 24) * (1.0f / 255.0f);
            }
            float an0 = 1.0f - (1.0f - ap0) * (1.0f - d0);
            float an1 = 1.0f - (1.0f - ap1) * (1.0f - d1);
            float an2 = 1.0f - (1.0f - ap2) * (1.0f - d2);
            float an3 = 1.0f - (1.0f - ap3) * (1.0f - d3);
            if (ITER == 1) {
                unsigned int b0 = __float2uint_rn(__saturatef(an0) * 255.0f);
                unsigned int b1 = __float2uint_rn(__saturatef(an1) * 255.0f);
                unsigned int b2 = __float2uint_rn(__saturatef(an2) * 255.0f);
                unsigned int b3 = __float2uint_rn(__saturatef(an3) * 255.0f);
                Tdst[gn] = b0 | (b1 << 8) | (b2 << 16) | (b3 << 24);
            } else {
                outP[gn] = an0;
                outP[NN + gn] = an1;
                outP[2 * NN + gn] = an2;
                outP[3 * NN + gn] = an3;
            }
        }
    }
}

extern "C" void kernel_launch(void* const* d_in, const int* in_sizes, int n_in,
                              void* d_out, int out_size, void* d_ws, size_t ws_size,
                              hipStream_t stream) {
    const float* a0 = (const float*)d_in[0];
    const float* W = (const float*)d_in[1];
    const int* X1 = (const int*)d_in[2];   // int64 in ref -> int32 on device
    const int* X2 = (const int*)d_in[3];
    float* out = (float*)d_out;

    // ws: pi_pk @0 (16,384) | pi_t_pk @16,384 (16,384) | pi1_pk @32,768 (256)
    // | pi2_pk @33,024 (256) | T0 @33,280 (80,000) | T1 @113,280 (80,000)
    if (ws_size < (size_t)193280) return;  // R5 measured ws >= 20.8 MB
    unsigned int* pi_pk  = (unsigned int*)d_ws;
    unsigned int* pi_t   = (unsigned int*)((char*)d_ws + 16384);
    unsigned int* pi1_pk = (unsigned int*)((char*)d_ws + 32768);
    unsigned int* pi2_pk = (unsigned int*)((char*)d_ws + 33024);
    unsigned int* T0     = (unsigned int*)((char*)d_ws + 33280);
    unsigned int* T1     = (unsigned int*)((char*)d_ws + 113280);

    prep_kernel<<<1, 1024, 0, stream>>>(W, pi_pk, pi_t, pi1_pk, pi2_pk);
    pack_kernel<<<20, 1024, 0, stream>>>(a0, T0);
    fused_iter<1><<<256, 1024, 0, stream>>>(T0, X1, X2, pi_t, pi1_pk, pi2_pk,
                                            a0, T1, nullptr);
    fused_iter<2><<<256, 1024, 0, stream>>>(T1, X1, X2, pi_t, pi1_pk, pi2_pk,
                                            nullptr, nullptr, out);
}

// Round 11
// 249.974 us; speedup vs baseline: 1.0328x; 1.0328x over previous
//
#include <hip/hip_runtime.h>

#define NN 20000
#define COLS 40
#define CPAD 41

typedef _Float16 f16x2 __attribute__((ext_vector_type(2)));
typedef unsigned short u16x2 __attribute__((ext_vector_type(2)));

union U32H2 { unsigned int u; f16x2 h; };
union U32S2 { unsigned int u; u16x2 s; };

__device__ __forceinline__ f16x2 bc_h2(unsigned int u) { U32H2 x; x.u = u; return x.h; }
__device__ __forceinline__ unsigned int dup_h(float v) {
    _Float16 h = (_Float16)v;
    unsigned short b = __builtin_bit_cast(unsigned short, h);
    return ((unsigned int)b << 16) | b;
}
__device__ __forceinline__ unsigned int pkrtz_u32(float a, float b) {
    return __builtin_bit_cast(unsigned int, __builtin_amdgcn_cvt_pkrtz(a, b));
}

template <int CTRL>
__device__ __forceinline__ unsigned int pkmax_dpp(unsigned int v) {
    unsigned int d = (unsigned int)__builtin_amdgcn_update_dpp(
        0, (int)v, CTRL, 0xF, 0xF, true);
    U32S2 a, b; a.u = v; b.u = d;
    a.s = __builtin_elementwise_max(a.s, b.s);
    return a.u;
}
__device__ __forceinline__ unsigned int octmax_u16x2(unsigned int v) {
    v = pkmax_dpp<0xB1>(v);    // quad_perm xor1
    v = pkmax_dpp<0x4E>(v);    // quad_perm xor2
    v = pkmax_dpp<0x141>(v);   // row_half_mirror (xor4 within 8)
    return v;
}

// ---------------- prep: softmax(W) -> packed-f16 pi tables ----------------
__global__ __launch_bounds__(1024) void prep_kernel(const float* __restrict__ W,
                                                    unsigned int* __restrict__ pi_pk,
                                                    unsigned int* __restrict__ pi_t_pk,
                                                    unsigned int* __restrict__ pi1_pk,
                                                    unsigned int* __restrict__ pi2_pk) {
    __shared__ float red[1024];
    __shared__ float piL[4096];
    int t = threadIdx.x;
    float4 wv = ((const float4*)W)[t];
    float m = fmaxf(fmaxf(wv.x, wv.y), fmaxf(wv.z, wv.w));
    red[t] = m; __syncthreads();
    for (int s = 512; s > 0; s >>= 1) {
        if (t < s) red[t] = fmaxf(red[t], red[t + s]);
        __syncthreads();
    }
    m = red[0];
    __syncthreads();
    float e0 = expf(wv.x - m), e1 = expf(wv.y - m);
    float e2 = expf(wv.z - m), e3 = expf(wv.w - m);
    red[t] = e0 + e1 + e2 + e3;
    __syncthreads();
    for (int s = 512; s > 0; s >>= 1) {
        if (t < s) red[t] += red[t + s];
        __syncthreads();
    }
    float inv = 1.0f / red[0];
    float p[4] = { e0 * inv, e1 * inv, e2 * inv, e3 * inv };
#pragma unroll
    for (int i = 0; i < 4; i++) {
        int f = t * 4 + i;
        piL[f] = p[i];
        unsigned int d = dup_h(p[i]);
        pi_pk[f] = d;
        pi_t_pk[(f & 63) * 64 + (f >> 6)] = d;  // transposed [k][j]
    }
    __syncthreads();
    if (t < 64) {
        float s = 0.f;
        for (int k = 0; k < 64; k++) s += piL[t * 64 + k];
        pi1_pk[t] = dup_h(s);
    } else if (t < 128) {
        int k = t - 64;
        float s = 0.f;
        for (int j = 0; j < 64; j++) s += piL[j * 64 + k];
        pi2_pk[k] = dup_h(s);
    }
}

// ---------------- pack a0 fp32 (B,N) planes -> u8x4 table ----------------
__global__ __launch_bounds__(1024) void pack_kernel(const float* __restrict__ a0,
                                                    unsigned int* __restrict__ T0) {
    int i = blockIdx.x * 1024 + threadIdx.x;
    if (i < NN) {
        unsigned int b0 = __float2uint_rn(__saturatef(a0[i]) * 255.0f);
        unsigned int b1 = __float2uint_rn(__saturatef(a0[NN + i]) * 255.0f);
        unsigned int b2 = __float2uint_rn(__saturatef(a0[2 * NN + i]) * 255.0f);
        unsigned int b3 = __float2uint_rn(__saturatef(a0[3 * NN + i]) * 255.0f);
        T0[i] = b0 | (b1 << 8) | (b2 << 16) | (b3 << 24);
    }
}

// ---------------- phase 1: clause gathers, depth-2 X prefetch ----------------
__device__ __forceinline__ void phase1(
    const unsigned int* __restrict__ tab,
    unsigned int (* __restrict__ Ftb)[2][CPAD],
    const int* __restrict__ X1, const int* __restrict__ X2,
    int nb, int cn, int widu, int ni, int w) {
    const float sc = 1.0f / 65025.0f;
    int loff[5];
#pragma unroll
    for (int oc = 0; oc < 5; ++oc) {
        int n = nb + oc * 8 + ni;
        int nc = n < NN ? n : NN - 1;
        loff[oc] = nc * 64 + w * 8;
    }
    int2 qb[2][5];
#pragma unroll
    for (int d = 0; d < 2; ++d) {
        const int row = widu + 16 * d, k = row & 63;
        const char* Xb = (const char*)((row >> 6) ? X2 : X1) + (unsigned)(k * NN) * 64u;
#pragma unroll
        for (int oc = 0; oc < 5; ++oc) qb[d][oc] = *(const int2*)(Xb + loff[oc]);
    }
#pragma unroll
    for (int rr = 0; rr < 8; ++rr) {
        const int cur = rr & 1;
        // issue this row's 10 LDS gathers (addresses from 2-iter-old loads)
        unsigned int ga[5], gb[5];
#pragma unroll
        for (int oc = 0; oc < 5; ++oc) {
            ga[oc] = tab[qb[cur][oc].x];
            gb[oc] = tab[qb[cur][oc].y];
        }
        // refill the slot with row rr+2 (keeps 10 X loads in flight)
        if (rr < 6) {
            const int row2 = widu + 16 * (rr + 2), k2 = row2 & 63;
            const char* Xb = (const char*)((row2 >> 6) ? X2 : X1)
                           + (unsigned)(k2 * NN) * 64u;
#pragma unroll
            for (int oc = 0; oc < 5; ++oc) qb[cur][oc] = *(const int2*)(Xb + loff[oc]);
        }
        const int row = widu + 16 * rr;
#pragma unroll
        for (int oc = 0; oc < 5; ++oc) {
            unsigned int ea = ga[oc] & 0x00FF00FFu;
            unsigned int oa = (ga[oc] >> 8) & 0x00FF00FFu;
            unsigned int eb = gb[oc] & 0x00FF00FFu;
            unsigned int ob = (gb[oc] >> 8) & 0x00FF00FFu;
            U32S2 pe, po, xb;
            pe.u = ea; xb.u = eb; pe.s = pe.s * xb.s;
            po.u = oa; xb.u = ob; po.s = po.s * xb.s;
            unsigned int peu = octmax_u16x2(pe.u);
            unsigned int pou = octmax_u16x2(po.u);
            int col = oc * 8 + ni;
            if (w == 0 && col < cn) {
                float f0 = (float)(peu & 0xFFFFu) * sc;   // b0
                float f1 = (float)(pou & 0xFFFFu) * sc;   // b1
                float f2 = (float)(peu >> 16) * sc;       // b2
                float f3 = (float)(pou >> 16) * sc;       // b3
                // [row][bp][col] layout: phase2 lanes stride 4B -> all 32 banks
                Ftb[row][0][col] = pkrtz_u32(f0, f1);
                Ftb[row][1][col] = pkrtz_u32(f2, f3);
            }
        }
    }
}

// ---------------- phase 2: bilinear partials for (qu, bp, n_l) ----------------
__device__ __forceinline__ float2 phase2(
    const unsigned int (* __restrict__ Ftb)[2][CPAD],
    const unsigned int* __restrict__ pi_t_pk,
    const unsigned int* __restrict__ pi1_pk,
    const unsigned int* __restrict__ pi2_pk,
    int qu, int bp, int n_l) {
    f16x2 zero = {(_Float16)0, (_Float16)0};
    f16x2 f1v[8];
    f16x2 eu = zero;
#pragma unroll
    for (int jj = 0; jj < 8; ++jj) {
        f1v[jj] = bc_h2(Ftb[qu * 8 + jj][bp][n_l]);
        eu += bc_h2(pi1_pk[qu * 8 + jj]) * f1v[jj];  // s_load
    }
    f16x2 euv = zero, ev = zero;
#pragma unroll 8
    for (int k = 0; k < 64; ++k) {
        f16x2 f2 = bc_h2(Ftb[64 + k][bp][n_l]);
        const uint4* pt = (const uint4*)(pi_t_pk + k * 64 + qu * 8);
        uint4 w0 = pt[0], w1 = pt[1];  // scalar addr -> s_load_dwordx4
        f16x2 ts = bc_h2(w0.x) * f1v[0] + bc_h2(w0.y) * f1v[1] +
                   bc_h2(w0.z) * f1v[2] + bc_h2(w0.w) * f1v[3] +
                   bc_h2(w1.x) * f1v[4] + bc_h2(w1.y) * f1v[5] +
                   bc_h2(w1.z) * f1v[6] + bc_h2(w1.w) * f1v[7];
        euv += f2 * ts;
        if (qu == 0) ev += bc_h2(pi2_pk[k]) * f2;
    }
    float p0 = (float)eu[0] - (float)euv[0];
    float p1 = (float)eu[1] - (float)euv[1];
    if (qu == 0) { p0 += (float)ev[0]; p1 += (float)ev[1]; }
    return make_float2(p0, p1);
}

// ---------------- fused predicate_forward iteration ----------------
template <int ITER>
__global__ __launch_bounds__(1024, 4) void fused_iter(
    const unsigned int* __restrict__ Tsrc,
    const int* __restrict__ X1, const int* __restrict__ X2,
    const unsigned int* __restrict__ pi_t_pk,
    const unsigned int* __restrict__ pi1_pk,
    const unsigned int* __restrict__ pi2_pk,
    const float* __restrict__ a0,
    unsigned int* __restrict__ Tdst, float* __restrict__ outP) {
    __shared__ unsigned int tab[NN];            // 80,000 B
    __shared__ unsigned int Ft[128][2][CPAD];   // 41,984 B
    __shared__ float redp[8][64][4];            //  8,192 B  (total 130,176)

    const int t = threadIdx.x;
    for (int i = t; i < NN; i += 1024) tab[i] = Tsrc[i];

    const int bid = (int)blockIdx.x;
    const int bstart = bid < 32 ? bid * 79 : 32 * 79 + (bid - 32) * 78;
    const int bcnt = bid < 32 ? 79 : 78;
    const int c0 = (bcnt + 1) >> 1;  // 40 or 39

    const int wid = t >> 6, lane = t & 63, ni = lane >> 3, w = lane & 7;
    const int q = t >> 7, bp = (t >> 6) & 1, n_l = t & 63;
    const int widu = __builtin_amdgcn_readfirstlane(wid);
    const int qu = __builtin_amdgcn_readfirstlane(q);

    __syncthreads();  // tab ready

    for (int ch = 0; ch < 2; ++ch) {
        const int nb = bstart + (ch ? c0 : 0);
        const int cn = ch ? (bcnt - c0) : c0;

        phase1(tab, Ft, X1, X2, nb, cn, widu, ni, w);
        __syncthreads();

        if (n_l < cn) {
            float2 pp = phase2(Ft, pi_t_pk, pi1_pk, pi2_pk, qu, bp, n_l);
            *(float2*)&redp[q][n_l][bp * 2] = pp;
        }
        __syncthreads();

        // combine + soft-OR (redp safe: next write is after next barrier)
        if (t < cn) {
            int gn = nb + t;
            float d0 = 0.f, d1 = 0.f, d2 = 0.f, d3 = 0.f;
#pragma unroll
            for (int q8 = 0; q8 < 8; ++q8) {
                d0 += redp[q8][t][0];
                d1 += redp[q8][t][1];
                d2 += redp[q8][t][2];
                d3 += redp[q8][t][3];
            }
            float ap0, ap1, ap2, ap3;
            if (ITER == 1) {
                ap0 = a0[gn]; ap1 = a0[NN + gn];
                ap2 = a0[2 * NN + gn]; ap3 = a0[3 * NN + gn];
            } else {
                unsigned int tv = tab[gn];
                ap0 = (float)(tv & 255u) * (1.0f / 255.0f);
                ap1 = (float)((tv >> 8) & 255u) * (1.0f / 255.0f);
                ap2 = (float)((tv >> 16) & 255u) * (1.0f / 255.0f);
                ap3 = (float)(tv >> 24) * (1.0f / 255.0f);
            }
            float an0 = 1.0f - (1.0f - ap0) * (1.0f - d0);
            float an1 = 1.0f - (1.0f - ap1) * (1.0f - d1);
            float an2 = 1.0f - (1.0f - ap2) * (1.0f - d2);
            float an3 = 1.0f - (1.0f - ap3) * (1.0f - d3);
            if (ITER == 1) {
                unsigned int b0 = __float2uint_rn(__saturatef(an0) * 255.0f);
                unsigned int b1 = __float2uint_rn(__saturatef(an1) * 255.0f);
                unsigned int b2 = __float2uint_rn(__saturatef(an2) * 255.0f);
                unsigned int b3 = __float2uint_rn(__saturatef(an3) * 255.0f);
                Tdst[gn] = b0 | (b1 << 8) | (b2 << 16) | (b3 << 24);
            } else {
                outP[gn] = an0;
                outP[NN + gn] = an1;
                outP[2 * NN + gn] = an2;
                outP[3 * NN + gn] = an3;
            }
        }
    }
}

extern "C" void kernel_launch(void* const* d_in, const int* in_sizes, int n_in,
                              void* d_out, int out_size, void* d_ws, size_t ws_size,
                              hipStream_t stream) {
    const float* a0 = (const float*)d_in[0];
    const float* W = (const float*)d_in[1];
    const int* X1 = (const int*)d_in[2];   // int64 in ref -> int32 on device
    const int* X2 = (const int*)d_in[3];
    float* out = (float*)d_out;

    // ws: pi_pk @0 (16,384) | pi_t_pk @16,384 (16,384) | pi1_pk @32,768 (256)
    // | pi2_pk @33,024 (256) | T0 @33,280 (80,000) | T1 @113,280 (80,000)
    if (ws_size < (size_t)193280) return;  // R5 measured ws >= 20.8 MB
    unsigned int* pi_pk  = (unsigned int*)d_ws;
    unsigned int* pi_t   = (unsigned int*)((char*)d_ws + 16384);
    unsigned int* pi1_pk = (unsigned int*)((char*)d_ws + 32768);
    unsigned int* pi2_pk = (unsigned int*)((char*)d_ws + 33024);
    unsigned int* T0     = (unsigned int*)((char*)d_ws + 33280);
    unsigned int* T1     = (unsigned int*)((char*)d_ws + 113280);

    prep_kernel<<<1, 1024, 0, stream>>>(W, pi_pk, pi_t, pi1_pk, pi2_pk);
    pack_kernel<<<20, 1024, 0, stream>>>(a0, T0);
    fused_iter<1><<<256, 1024, 0, stream>>>(T0, X1, X2, pi_t, pi1_pk, pi2_pk,
                                            a0, T1, nullptr);
    fused_iter<2><<<256, 1024, 0, stream>>>(T1, X1, X2, pi_t, pi1_pk, pi2_pk,
                                            nullptr, nullptr, out);
}